// Round 2
// baseline (319.686 us; speedup 1.0000x reference)
//
#include <hip/hip_runtime.h>

#define DM 256
#define NNODE 128
#define NB 8

typedef __attribute__((ext_vector_type(8))) __bf16 bf16x8;
typedef __attribute__((ext_vector_type(4))) __bf16 bf16x4;
typedef __attribute__((ext_vector_type(4))) float f32x4;

__device__ __forceinline__ float fast_sig(float x) {
  return __builtin_amdgcn_rcpf(1.0f + __expf(-x));
}
__device__ __forceinline__ float siluf(float x) { return x * fast_sig(x); }

// ---------------- weight conversion + workspace zeroing ----------------
__global__ __launch_bounds__(256) void k_prep(
    const float* __restrict__ We1, const float* __restrict__ Wx1,
    const float* __restrict__ We2, const float* __restrict__ Wx2,
    __bf16* __restrict__ wt_e, __bf16* __restrict__ wt_x,
    __bf16* __restrict__ w2e, __bf16* __restrict__ w2x,
    float* __restrict__ nmsg, float* __restrict__ cupd)
{
  int idx = blockIdx.x * 256 + threadIdx.x;   // 0..65535
  if (idx < 16384) {                          // [256 c][64 k] tails (rows 512..575)
    int c = idx >> 6, k = idx & 63;
    wt_e[idx] = (__bf16)We1[(512 + k) * 256 + c];
    wt_x[idx] = (__bf16)Wx1[(512 + k) * 256 + c];
  }
  {                                           // [256 c][256 k]
    int c = idx >> 8, k = idx & 255;
    w2e[idx] = (__bf16)We2[k * 256 + c];
    w2x[idx] = (__bf16)Wx2[k * 256 + c];
  }
  f32x4 z = {0.f, 0.f, 0.f, 0.f};
  *(f32x4*)(nmsg + idx * 4) = z;              // 262144 floats
  if (idx < 3072) cupd[idx] = 0.f;
}

// ---------------- node projections: hi_e(+b), hj_e, hi_x(+b), hj_x ----------------
__global__ __launch_bounds__(256) void k_nodes(
    const float* __restrict__ invf, const float* __restrict__ We1,
    const float* __restrict__ Wx1, const float* __restrict__ be1,
    const float* __restrict__ bx1,
    float* __restrict__ hie, float* __restrict__ hje,
    float* __restrict__ hix, float* __restrict__ hjx)
{
  __shared__ float sInv[4][256];
  int c = threadIdx.x;
  int node0 = blockIdx.x * 4;
  #pragma unroll
  for (int nn = 0; nn < 4; nn++)
    sInv[nn][c] = invf[(node0 + nn) * 256 + c];
  __syncthreads();
  float aie[4] = {0,0,0,0}, aje[4] = {0,0,0,0}, aix[4] = {0,0,0,0}, ajx[4] = {0,0,0,0};
  #pragma unroll 4
  for (int k = 0; k < 256; k++) {
    float wie = We1[k * 256 + c];
    float wje = We1[(256 + k) * 256 + c];
    float wix = Wx1[k * 256 + c];
    float wjx = Wx1[(256 + k) * 256 + c];
    #pragma unroll
    for (int nn = 0; nn < 4; nn++) {
      float v = sInv[nn][k];
      aie[nn] += v * wie; aje[nn] += v * wje;
      aix[nn] += v * wix; ajx[nn] += v * wjx;
    }
  }
  #pragma unroll
  for (int nn = 0; nn < 4; nn++) {
    hie[(node0 + nn) * 256 + c] = aie[nn] + be1[c];
    hje[(node0 + nn) * 256 + c] = aje[nn];
    hix[(node0 + nn) * 256 + c] = aix[nn] + bx1[c];
    hjx[(node0 + nn) * 256 + c] = ajx[nn];
  }
}

// ---------------- one edge-MLP path (swapped operands: output is [c][j]) ----------------
template<bool EPATH>
__device__ __forceinline__ void egnn_path(
    int tid,
    const __bf16* sE, char* sSb,
    const float* shi, const float* slast, const float* sqv,
    const float* __restrict__ hjb,          // + (b*128 + j0g)*256
    const __bf16* __restrict__ wt,          // [256 c][64 k]
    const __bf16* __restrict__ w2,          // [256 c][256 k]
    const float* __restrict__ bias2,        // b_e2 / b_x2 (global)
    const float* __restrict__ vvec,         // W_att / W_x3 (global)
    float* sRed, float battb,
    float* sAttW, float* sNM,
    const float* __restrict__ adjrow,       // + bi*128 + j0g
    float* __restrict__ nmsg_out)           // + bi*256
{
  const int lane = tid & 63;
  const int w = tid >> 6;
  const int lr = lane & 15;
  const int lg = lane >> 4;
  const int c0 = (w & 3) * 64;     // 4 c-tiles of 16 (n)
  const int jw = (w >> 2) * 32;    // 2 j-tiles of 16 (m)

  // ---- GEMM1: D'[c][j] = W1t x Et,  K=64 ----
  f32x4 acc[2][4];
  #pragma unroll
  for (int m = 0; m < 2; m++)
    #pragma unroll
    for (int n = 0; n < 4; n++) { f32x4 z = {0.f,0.f,0.f,0.f}; acc[m][n] = z; }

  #pragma unroll
  for (int ks = 0; ks < 2; ks++) {
    bf16x8 bE[2], aW[4];
    #pragma unroll
    for (int m = 0; m < 2; m++)
      bE[m] = *(const bf16x8*)(sE + (jw + m * 16 + lr) * 72 + ks * 32 + lg * 8);
    #pragma unroll
    for (int n = 0; n < 4; n++)
      aW[n] = *(const bf16x8*)(wt + (c0 + n * 16 + lr) * 64 + ks * 32 + lg * 8);
    #pragma unroll
    for (int m = 0; m < 2; m++)
      #pragma unroll
      for (int n = 0; n < 4; n++)
        acc[m][n] = __builtin_amdgcn_mfma_f32_16x16x32_bf16(aW[n], bE[m], acc[m][n], 0, 0, 0);
  }

  // epilogue1: v = acc + hi[c] + hj[j][c] + sq[j]*w_last[c]; silu; -> sSb (bf16, swizzled)
  #pragma unroll
  for (int m = 0; m < 2; m++) {
    const int j = jw + m * 16 + lr;
    const float sq = sqv[j];
    #pragma unroll
    for (int n = 0; n < 4; n++) {
      const int cb = c0 + n * 16 + lg * 4;
      f32x4 hj4 = *(const f32x4*)(hjb + j * 256 + cb);
      f32x4 hi4 = *(const f32x4*)(shi + cb);
      f32x4 sl4 = *(const f32x4*)(slast + cb);
      bf16x4 pk;
      #pragma unroll
      for (int r = 0; r < 4; r++) {
        float v = acc[m][n][r] + hi4[r] + hj4[r] + sq * sl4[r];
        pk[r] = (__bf16)siluf(v);
      }
      int off = (j * 512 + cb * 2) ^ ((j & 7) << 4);
      *(bf16x4*)(sSb + off) = pk;
    }
  }
  __syncthreads();

  // ---- GEMM2: D'[c][j] = W2t x St,  K=256 ----
  #pragma unroll
  for (int m = 0; m < 2; m++)
    #pragma unroll
    for (int n = 0; n < 4; n++) { f32x4 z = {0.f,0.f,0.f,0.f}; acc[m][n] = z; }

  for (int ks = 0; ks < 8; ks++) {
    bf16x8 bS[2], aW[4];
    #pragma unroll
    for (int m = 0; m < 2; m++) {
      const int j = jw + m * 16 + lr;
      int off = (j * 512 + (ks * 32 + lg * 8) * 2) ^ ((j & 7) << 4);
      bS[m] = *(const bf16x8*)(sSb + off);
    }
    #pragma unroll
    for (int n = 0; n < 4; n++)
      aW[n] = *(const bf16x8*)(w2 + (c0 + n * 16 + lr) * 256 + ks * 32 + lg * 8);
    #pragma unroll
    for (int m = 0; m < 2; m++)
      #pragma unroll
      for (int n = 0; n < 4; n++)
        acc[m][n] = __builtin_amdgcn_mfma_f32_16x16x32_bf16(aW[n], bS[m], acc[m][n], 0, 0, 0);
  }

  // epilogue2: silu(+bias2), row-dot with vvec -> sRed[j]
  f32x4 bb[4], vv[4];
  #pragma unroll
  for (int n = 0; n < 4; n++) {
    bb[n] = *(const f32x4*)(bias2 + c0 + n * 16 + lg * 4);
    vv[n] = *(const f32x4*)(vvec  + c0 + n * 16 + lg * 4);
  }
  float p[2] = {0.f, 0.f};
  #pragma unroll
  for (int m = 0; m < 2; m++)
    #pragma unroll
    for (int n = 0; n < 4; n++)
      #pragma unroll
      for (int r = 0; r < 4; r++) {
        float s = siluf(acc[m][n][r] + bb[n][r]);
        acc[m][n][r] = s;
        p[m] += s * vv[n][r];
      }
  #pragma unroll
  for (int m = 0; m < 2; m++) {
    p[m] += __shfl_xor(p[m], 16);
    p[m] += __shfl_xor(p[m], 32);
  }
  if (lg == 0) {
    #pragma unroll
    for (int m = 0; m < 2; m++)
      atomicAdd(&sRed[jw + m * 16 + lr], p[m]);
  }
  __syncthreads();

  if constexpr (EPATH) {
    if (tid < 64)
      sAttW[tid] = fast_sig(sRed[tid] + battb) * adjrow[tid];
    __syncthreads();
    float aw[2];
    #pragma unroll
    for (int m = 0; m < 2; m++) aw[m] = sAttW[jw + m * 16 + lr];
    f32x4 q[4];
    #pragma unroll
    for (int n = 0; n < 4; n++) { f32x4 z = {0.f,0.f,0.f,0.f}; q[n] = z; }
    #pragma unroll
    for (int m = 0; m < 2; m++)
      #pragma unroll
      for (int n = 0; n < 4; n++)
        q[n] += acc[m][n] * aw[m];
    #pragma unroll
    for (int off = 1; off < 16; off <<= 1)
      #pragma unroll
      for (int n = 0; n < 4; n++)
        #pragma unroll
        for (int r = 0; r < 4; r++)
          q[n][r] += __shfl_xor(q[n][r], off);
    #pragma unroll
    for (int n = 0; n < 4; n++)
      #pragma unroll
      for (int r = 0; r < 4; r++)
        if (lr == n * 4 + r) atomicAdd(&sNM[c0 + n * 16 + lg * 4 + r], q[n][r]);
    __syncthreads();
    if (tid < 256) atomicAdd(nmsg_out + tid, sNM[tid]);
  }
}

// ---------------- main edge kernel: one block = 64 j-rows of one (b,i) ----------------
__global__ __launch_bounds__(512, 6) void k_edge(
    const float* __restrict__ coords, const float* __restrict__ adjm,
    const float* __restrict__ ef,
    const float* __restrict__ We1, const float* __restrict__ Wx1,
    const float* __restrict__ Watt, const float* __restrict__ batt,
    const float* __restrict__ be2, const float* __restrict__ bx2,
    const float* __restrict__ bx3,
    const float* __restrict__ hie, const float* __restrict__ hje,
    const float* __restrict__ hix, const float* __restrict__ hjx,
    const __bf16* __restrict__ wt_e, const __bf16* __restrict__ wt_x,
    const __bf16* __restrict__ w2e, const __bf16* __restrict__ w2x,
    const float* __restrict__ Wx3,
    float* __restrict__ nmsg, float* __restrict__ cupd)
{
  __shared__ __align__(16) __bf16 sE[64 * 72];
  __shared__ __align__(16) char sSb[64 * 512];
  __shared__ float shie[256], shix[256], slaste[256], slastx[256];
  __shared__ float sqv[64], sRed1[64], sRed2[64], sAttW[64], sNM[256];

  const int tid = threadIdx.x;
  const int bi = blockIdx.x >> 1;       // b*128 + i
  const int half = blockIdx.x & 1;
  const int b = bi >> 7;
  const int j0g = half * 64;            // global j offset of this block

  const float cix = coords[bi * 3 + 0];
  const float ciy = coords[bi * 3 + 1];
  const float ciz = coords[bi * 3 + 2];

  if (tid < 64) { sRed1[tid] = 0.f; sRed2[tid] = 0.f; }
  if (tid >= 64 && tid < 320) sNM[tid - 64] = 0.f;
  if (tid < 256) {
    shie[tid] = hie[(size_t)bi * 256 + tid];
    shix[tid] = hix[(size_t)bi * 256 + tid];
    slaste[tid] = We1[576 * 256 + tid];
    slastx[tid] = Wx1[576 * 256 + tid];
  }
  if (tid >= 448) {
    int j = tid - 448;
    int jg = b * 128 + j0g + j;
    float dx = cix - coords[jg * 3 + 0];
    float dy = ciy - coords[jg * 3 + 1];
    float dz = ciz - coords[jg * 3 + 2];
    sqv[j] = dx * dx + dy * dy + dz * dz;
  }
  const float* efb = ef + ((size_t)bi * 128 + j0g) * 64;
  #pragma unroll
  for (int it = 0; it < 2; it++) {
    int idx = (tid + it * 512) * 4;
    f32x4 v = *(const f32x4*)(efb + idx);
    bf16x4 pk;
    pk[0] = (__bf16)v[0]; pk[1] = (__bf16)v[1];
    pk[2] = (__bf16)v[2]; pk[3] = (__bf16)v[3];
    *(bf16x4*)(sE + (idx >> 6) * 72 + (idx & 63)) = pk;
  }
  __syncthreads();

  const float* hjbase_e = hje + ((size_t)b * 128 + j0g) * 256;
  const float* hjbase_x = hjx + ((size_t)b * 128 + j0g) * 256;
  const float* adjrow = adjm + (size_t)bi * 128 + j0g;

  egnn_path<true>(tid, sE, sSb, shie, slaste, sqv, hjbase_e,
                  wt_e, w2e, be2, Watt, sRed1, batt[0], sAttW, sNM,
                  adjrow, nmsg + (size_t)bi * 256);
  egnn_path<false>(tid, sE, sSb, shix, slastx, sqv, hjbase_x,
                   wt_x, w2x, bx2, Wx3, sRed2, 0.f, sAttW, sNM,
                   adjrow, nmsg + (size_t)bi * 256);

  // ---- coord partial sums over this block's 64 j ----
  if (tid < 64) {
    int j = tid;
    int jg = b * 128 + j0g + j;
    float ea = sRed2[j] + bx3[0];
    float wgt = ea * __builtin_amdgcn_rcpf(sqrtf(sqv[j] + 1e-5f) + 1.0f) * adjrow[j];
    float wx = wgt * (cix - coords[jg * 3 + 0]);
    float wy = wgt * (ciy - coords[jg * 3 + 1]);
    float wz = wgt * (ciz - coords[jg * 3 + 2]);
    #pragma unroll
    for (int off = 1; off < 64; off <<= 1) {
      wx += __shfl_xor(wx, off);
      wy += __shfl_xor(wy, off);
      wz += __shfl_xor(wz, off);
    }
    if (tid == 0) {
      atomicAdd(&cupd[bi * 3 + 0], wx);
      atomicAdd(&cupd[bi * 3 + 1], wy);
      atomicAdd(&cupd[bi * 3 + 2], wz);
    }
  }
}

// ---------------- h-path + out_feats + coord finalize ----------------
__global__ __launch_bounds__(256) void k_h(
    const float* __restrict__ invf, const float* __restrict__ nmsg,
    const float* __restrict__ Wh1, const float* __restrict__ bh1,
    const float* __restrict__ Wh2, const float* __restrict__ bh2,
    const float* __restrict__ amask, const float* __restrict__ coords,
    const float* __restrict__ cupd,
    float* __restrict__ out_feats, float* __restrict__ out_coords)
{
  __shared__ float sIn[4][512];
  __shared__ float sH1[4][256];
  __shared__ float sNumS;
  int c = threadIdx.x;
  int node0 = blockIdx.x * 4;
  int b = node0 >> 7;
  #pragma unroll
  for (int nn = 0; nn < 4; nn++) {
    sIn[nn][c] = invf[(node0 + nn) * 256 + c];
    sIn[nn][256 + c] = nmsg[(node0 + nn) * 256 + c];
  }
  if (c < 64) {
    float nsum = amask[b * 128 + c] + amask[b * 128 + 64 + c];
    #pragma unroll
    for (int off = 1; off < 64; off <<= 1) nsum += __shfl_xor(nsum, off);
    if (c == 0) sNumS = nsum;
  }
  __syncthreads();
  float a1[4];
  #pragma unroll
  for (int nn = 0; nn < 4; nn++) a1[nn] = bh1[c];
  #pragma unroll 4
  for (int k = 0; k < 512; k++) {
    float wv = Wh1[k * 256 + c];
    #pragma unroll
    for (int nn = 0; nn < 4; nn++) a1[nn] += sIn[nn][k] * wv;
  }
  #pragma unroll
  for (int nn = 0; nn < 4; nn++) sH1[nn][c] = siluf(a1[nn]);
  __syncthreads();
  float a2[4];
  #pragma unroll
  for (int nn = 0; nn < 4; nn++) a2[nn] = bh2[c];
  #pragma unroll 4
  for (int k = 0; k < 256; k++) {
    float wv = Wh2[k * 256 + c];
    #pragma unroll
    for (int nn = 0; nn < 4; nn++) a2[nn] += sH1[nn][k] * wv;
  }
  #pragma unroll
  for (int nn = 0; nn < 4; nn++)
    out_feats[(node0 + nn) * 256 + c] = a2[nn] * amask[node0 + nn];
  if (c < 12) {
    int nn = c / 3, d = c % 3;
    int node = node0 + nn;
    float upd = cupd[node * 3 + d] / (sNumS + 1.0f);
    out_coords[node * 3 + d] = (coords[node * 3 + d] + upd) * amask[node];
  }
}

extern "C" void kernel_launch(void* const* d_in, const int* in_sizes, int n_in,
                              void* d_out, int out_size, void* d_ws, size_t ws_size,
                              hipStream_t stream)
{
  const float* coords = (const float*)d_in[0];
  const float* invf  = (const float*)d_in[1];
  const float* adjm  = (const float*)d_in[2];
  const float* amask = (const float*)d_in[3];
  const float* ef    = (const float*)d_in[4];
  const float* We1   = (const float*)d_in[5];
  const float* be1   = (const float*)d_in[6];
  const float* We2   = (const float*)d_in[7];
  const float* be2   = (const float*)d_in[8];
  const float* Watt  = (const float*)d_in[9];
  const float* batt  = (const float*)d_in[10];
  const float* Wh1   = (const float*)d_in[11];
  const float* bh1   = (const float*)d_in[12];
  const float* Wh2   = (const float*)d_in[13];
  const float* bh2   = (const float*)d_in[14];
  const float* Wx1   = (const float*)d_in[15];
  const float* bx1   = (const float*)d_in[16];
  const float* Wx2   = (const float*)d_in[17];
  const float* bx2   = (const float*)d_in[18];
  const float* Wx3   = (const float*)d_in[19];
  const float* bx3   = (const float*)d_in[20];

  char* ws = (char*)d_ws;
  float* hie  = (float*)(ws + (size_t)0);
  float* hje  = (float*)(ws + (size_t)(1u << 20));
  float* hix  = (float*)(ws + (size_t)(2u << 20));
  float* hjx  = (float*)(ws + (size_t)(3u << 20));
  float* nmsg = (float*)(ws + (size_t)(4u << 20));
  float* cupd = (float*)(ws + (size_t)(5u << 20));
  __bf16* wt_e = (__bf16*)(ws + (size_t)(5u << 20) + 65536);
  __bf16* wt_x = (__bf16*)(ws + (size_t)(5u << 20) + 65536 + 32768);
  __bf16* w2e  = (__bf16*)(ws + (size_t)(5u << 20) + 65536 + 65536);
  __bf16* w2x  = (__bf16*)(ws + (size_t)(5u << 20) + 65536 + 65536 + 131072);

  float* out_coords = (float*)d_out;
  float* out_feats  = out_coords + NB * NNODE * 3;

  hipLaunchKernelGGL(k_prep, dim3(256), dim3(256), 0, stream,
                     We1, Wx1, We2, Wx2, wt_e, wt_x, w2e, w2x, nmsg, cupd);
  hipLaunchKernelGGL(k_nodes, dim3(256), dim3(256), 0, stream,
                     invf, We1, Wx1, be1, bx1, hie, hje, hix, hjx);
  hipLaunchKernelGGL(k_edge, dim3(2048), dim3(512), 0, stream,
                     coords, adjm, ef, We1, Wx1, Watt, batt, be2, bx2, bx3,
                     hie, hje, hix, hjx, wt_e, wt_x, w2e, w2x, Wx3, nmsg, cupd);
  hipLaunchKernelGGL(k_h, dim3(256), dim3(256), 0, stream,
                     invf, nmsg, Wh1, bh1, Wh2, bh2, amask, coords, cupd,
                     out_feats, out_coords);
}

// Round 3
// 202.234 us; speedup vs baseline: 1.5808x; 1.5808x over previous
//
#include <hip/hip_runtime.h>

typedef __attribute__((ext_vector_type(8))) __bf16 bf16x8;
typedef __attribute__((ext_vector_type(4))) __bf16 bf16x4;
typedef __attribute__((ext_vector_type(4))) float f32x4;

__device__ __forceinline__ float fast_sig(float x) {
  return __builtin_amdgcn_rcpf(1.0f + __expf(-x));
}
__device__ __forceinline__ float siluf(float x) { return x * fast_sig(x); }
__device__ __forceinline__ __bf16 tobf(float x) { return (__bf16)x; }

// ================= k_prep: all weight transposes to bf16 [out][k] =================
__global__ __launch_bounds__(256) void k_prep(
    const float* __restrict__ We1, const float* __restrict__ Wx1,
    const float* __restrict__ We2, const float* __restrict__ Wx2,
    const float* __restrict__ Wh1, const float* __restrict__ Wh2,
    const float* __restrict__ invf,
    __bf16* __restrict__ wt_e, __bf16* __restrict__ wt_x,
    __bf16* __restrict__ w2e, __bf16* __restrict__ w2x,
    __bf16* __restrict__ wh1t, __bf16* __restrict__ wh2t,
    __bf16* __restrict__ hcat)
{
  int idx = blockIdx.x * 256 + threadIdx.x;          // 0..262143
  if (idx < 147456) {                                // [256 kk][576 f]
    int kk = idx / 576, f = idx - kk * 576;
    wt_e[idx] = tobf(We1[f * 256 + kk]);
    wt_x[idx] = tobf(Wx1[f * 256 + kk]);
  }
  if (idx < 65536) {                                 // [256 c][256 k]
    int c = idx >> 8, k = idx & 255;
    w2e[idx] = tobf(We2[k * 256 + c]);
    w2x[idx] = tobf(Wx2[k * 256 + c]);
    wh2t[idx] = tobf(Wh2[k * 256 + c]);
  }
  if (idx < 131072) {                                // [256 c][512 k]
    int c = idx >> 9, k = idx & 511;
    wh1t[idx] = tobf(Wh1[k * 256 + c]);
  }
  {                                                  // hcat[:,0:256] = bf16(invf)
    int node = idx >> 8, k = idx & 255;
    hcat[node * 512 + k] = tobf(invf[idx]);
  }
}

// ============ generic node GEMM: 64-row tile, 256 thr, out[c][node], no LDS ============
template<int NKS>
__device__ __forceinline__ void node_gemm64(
    const __bf16* __restrict__ B, int ldb, int boff,
    const __bf16* __restrict__ A, int lda, int aoff,
    int row0, int tid, f32x4 acc[4][4])
{
  const int lane = tid & 63, wc = tid >> 6, lr = lane & 15, lg = lane >> 4;
  #pragma unroll
  for (int ks = 0; ks < NKS; ks++) {
    bf16x8 bB[4], aA[4];
    #pragma unroll
    for (int m = 0; m < 4; m++)
      bB[m] = *(const bf16x8*)(B + (size_t)(row0 + m * 16 + lr) * ldb + boff + ks * 32 + lg * 8);
    #pragma unroll
    for (int n = 0; n < 4; n++)
      aA[n] = *(const bf16x8*)(A + (size_t)(wc * 64 + n * 16 + lr) * lda + aoff + ks * 32 + lg * 8);
    #pragma unroll
    for (int m = 0; m < 4; m++)
      #pragma unroll
      for (int n = 0; n < 4; n++)
        acc[m][n] = __builtin_amdgcn_mfma_f32_16x16x32_bf16(aA[n], bB[m], acc[m][n], 0, 0, 0);
  }
}

// ================= node projections (4 mats) =================
__global__ __launch_bounds__(256) void k_nproj(
    const __bf16* __restrict__ hcat,
    const __bf16* __restrict__ wt_e, const __bf16* __restrict__ wt_x,
    const float* __restrict__ be1, const float* __restrict__ bx1,
    float* __restrict__ hie, float* __restrict__ hje,
    float* __restrict__ hix, float* __restrict__ hjx)
{
  const int tid = threadIdx.x;
  const int row0 = blockIdx.x * 64;
  const int mat = blockIdx.y;
  const __bf16* A = (mat < 2) ? wt_e : wt_x;
  const int aoff = (mat & 1) ? 256 : 0;
  const float* bias = (mat == 0) ? be1 : (mat == 2 ? bx1 : nullptr);
  float* out = (mat == 0) ? hie : (mat == 1) ? hje : (mat == 2) ? hix : hjx;

  f32x4 acc[4][4];
  #pragma unroll
  for (int m = 0; m < 4; m++)
    #pragma unroll
    for (int n = 0; n < 4; n++) { f32x4 z = {0.f,0.f,0.f,0.f}; acc[m][n] = z; }
  node_gemm64<8>(hcat, 512, 0, A, 576, aoff, row0, tid, acc);

  const int lane = tid & 63, wc = tid >> 6, lr = lane & 15, lg = lane >> 4;
  #pragma unroll
  for (int m = 0; m < 4; m++) {
    int node = row0 + m * 16 + lr;
    #pragma unroll
    for (int n = 0; n < 4; n++) {
      int c0 = wc * 64 + n * 16 + lg * 4;
      f32x4 v = acc[m][n];
      if (bias) v += *(const f32x4*)(bias + c0);
      *(f32x4*)(out + (size_t)node * 256 + c0) = v;
    }
  }
}

// ================= h-path GEMM1: h1 = silu(hcat @ Wh1 + bh1), bf16 out =================
__global__ __launch_bounds__(256) void k_h1(
    const __bf16* __restrict__ hcat, const __bf16* __restrict__ wh1t,
    const float* __restrict__ bh1, __bf16* __restrict__ h1b)
{
  const int tid = threadIdx.x;
  const int row0 = blockIdx.x * 64;
  f32x4 acc[4][4];
  #pragma unroll
  for (int m = 0; m < 4; m++)
    #pragma unroll
    for (int n = 0; n < 4; n++) { f32x4 z = {0.f,0.f,0.f,0.f}; acc[m][n] = z; }
  node_gemm64<16>(hcat, 512, 0, wh1t, 512, 0, row0, tid, acc);

  const int lane = tid & 63, wc = tid >> 6, lr = lane & 15, lg = lane >> 4;
  #pragma unroll
  for (int m = 0; m < 4; m++) {
    int node = row0 + m * 16 + lr;
    #pragma unroll
    for (int n = 0; n < 4; n++) {
      int c0 = wc * 64 + n * 16 + lg * 4;
      f32x4 b4 = *(const f32x4*)(bh1 + c0);
      bf16x4 pk;
      #pragma unroll
      for (int r = 0; r < 4; r++) pk[r] = tobf(siluf(acc[m][n][r] + b4[r]));
      *(bf16x4*)(h1b + (size_t)node * 256 + c0) = pk;
    }
  }
}

// ===== h-path GEMM2 + mask + coord finalize =====
__global__ __launch_bounds__(256) void k_h2(
    const __bf16* __restrict__ h1b, const __bf16* __restrict__ wh2t,
    const float* __restrict__ bh2, const float* __restrict__ amask,
    const float* __restrict__ coords, const float* __restrict__ cupd,
    float* __restrict__ out_feats, float* __restrict__ out_coords)
{
  __shared__ float sM[2];
  const int tid = threadIdx.x;
  const int row0 = blockIdx.x * 64;
  const int b = row0 >> 7;
  f32x4 acc[4][4];
  #pragma unroll
  for (int m = 0; m < 4; m++)
    #pragma unroll
    for (int n = 0; n < 4; n++) { f32x4 z = {0.f,0.f,0.f,0.f}; acc[m][n] = z; }
  node_gemm64<8>(h1b, 256, 0, wh2t, 256, 0, row0, tid, acc);

  // num_nodes for this b
  if (tid < 128) {
    float v = amask[b * 128 + tid];
    #pragma unroll
    for (int off = 1; off < 64; off <<= 1) v += __shfl_xor(v, off);
    if ((tid & 63) == 0) sM[tid >> 6] = v;
  }
  __syncthreads();
  const float sNum = sM[0] + sM[1];

  const int lane = tid & 63, wc = tid >> 6, lr = lane & 15, lg = lane >> 4;
  #pragma unroll
  for (int m = 0; m < 4; m++) {
    int node = row0 + m * 16 + lr;
    float msk = amask[node];
    #pragma unroll
    for (int n = 0; n < 4; n++) {
      int c0 = wc * 64 + n * 16 + lg * 4;
      f32x4 b4 = *(const f32x4*)(bh2 + c0);
      f32x4 v = (acc[m][n] + b4) * msk;
      *(f32x4*)(out_feats + (size_t)node * 256 + c0) = v;
    }
  }
  if (tid < 192) {
    int nl = tid / 3, d = tid - nl * 3;
    int node = row0 + nl;
    float upd = cupd[node * 3 + d] / (sNum + 1.0f);
    out_coords[node * 3 + d] = (coords[node * 3 + d] + upd) * amask[node];
  }
}

// ================= edge-MLP path =================
template<bool EPATH>
__device__ __forceinline__ void egnn_path(
    int tid,
    const __bf16* sE, char* sSb,
    const float* shi, const float* slast, const float* sqv,
    const float* __restrict__ hjb,
    const __bf16* __restrict__ wt,          // [256 kk][576 f]
    const __bf16* __restrict__ w2,          // [256 c][256 k]
    const float* __restrict__ bias2,
    const float* __restrict__ vvec,
    float* sRed, const float* __restrict__ battp,
    float* sAttW, float* sNM,
    const float* __restrict__ adjrow,
    __bf16* __restrict__ hcat_out)          // hcat + bi*512 + 256
{
  const int lane = tid & 63;
  const int w = tid >> 6;            // 0..15
  const int lr = lane & 15, lg = lane >> 4;
  const int jw = (w >> 3) * 64;      // j half
  const int kb = (w & 7) * 32;       // kk base (GEMM1) == c base (GEMM2)

  // ---- GEMM1: S'[kk][j], K=65 (64 MFMA + sq rank-1) ----
  f32x4 acc1[4][2];
  #pragma unroll
  for (int m = 0; m < 4; m++)
    #pragma unroll
    for (int n = 0; n < 2; n++) { f32x4 z = {0.f,0.f,0.f,0.f}; acc1[m][n] = z; }
  #pragma unroll
  for (int ks = 0; ks < 2; ks++) {
    bf16x8 bE[4];
    #pragma unroll
    for (int m = 0; m < 4; m++)
      bE[m] = *(const bf16x8*)(sE + (jw + m * 16 + lr) * 72 + ks * 32 + lg * 8);
    #pragma unroll
    for (int n = 0; n < 2; n++) {
      bf16x8 aW = *(const bf16x8*)(wt + (size_t)(kb + n * 16 + lr) * 576 + 512 + ks * 32 + lg * 8);
      #pragma unroll
      for (int m = 0; m < 4; m++)
        acc1[m][n] = __builtin_amdgcn_mfma_f32_16x16x32_bf16(aW, bE[m], acc1[m][n], 0, 0, 0);
    }
  }
  // ep1: + hi + hj + sq*w_last, silu, bf16 -> swizzled LDS
  #pragma unroll
  for (int m = 0; m < 4; m++) {
    const int j = jw + m * 16 + lr;
    const float sq = sqv[j];
    #pragma unroll
    for (int n = 0; n < 2; n++) {
      const int kk0 = kb + n * 16 + lg * 4;
      f32x4 hj4 = *(const f32x4*)(hjb + (size_t)j * 256 + kk0);
      f32x4 hi4 = *(const f32x4*)(shi + kk0);
      f32x4 sl4 = *(const f32x4*)(slast + kk0);
      bf16x4 pk;
      #pragma unroll
      for (int r = 0; r < 4; r++)
        pk[r] = tobf(siluf(acc1[m][n][r] + hi4[r] + hj4[r] + sq * sl4[r]));
      int off = (j * 512 + kk0 * 2) ^ ((j & 7) << 4);
      *(bf16x4*)(sSb + off) = pk;
    }
  }
  __syncthreads();

  // ---- GEMM2: M'[c][j], K=256 ----
  f32x4 acc2[4][2];
  #pragma unroll
  for (int m = 0; m < 4; m++)
    #pragma unroll
    for (int n = 0; n < 2; n++) { f32x4 z = {0.f,0.f,0.f,0.f}; acc2[m][n] = z; }
  #pragma unroll
  for (int ks = 0; ks < 8; ks++) {
    bf16x8 bS[4];
    #pragma unroll
    for (int m = 0; m < 4; m++) {
      const int j = jw + m * 16 + lr;
      int off = (j * 512 + (ks * 32 + lg * 8) * 2) ^ ((j & 7) << 4);
      bS[m] = *(const bf16x8*)(sSb + off);
    }
    #pragma unroll
    for (int n = 0; n < 2; n++) {
      bf16x8 aW = *(const bf16x8*)(w2 + (size_t)(kb + n * 16 + lr) * 256 + ks * 32 + lg * 8);
      #pragma unroll
      for (int m = 0; m < 4; m++)
        acc2[m][n] = __builtin_amdgcn_mfma_f32_16x16x32_bf16(aW, bS[m], acc2[m][n], 0, 0, 0);
    }
  }

  // ep2: silu(+bias2), row-dot with vvec
  f32x4 bb[2], vv[2];
  #pragma unroll
  for (int n = 0; n < 2; n++) {
    bb[n] = *(const f32x4*)(bias2 + kb + n * 16 + lg * 4);
    vv[n] = *(const f32x4*)(vvec  + kb + n * 16 + lg * 4);
  }
  float p[4] = {0.f, 0.f, 0.f, 0.f};
  #pragma unroll
  for (int m = 0; m < 4; m++)
    #pragma unroll
    for (int n = 0; n < 2; n++)
      #pragma unroll
      for (int r = 0; r < 4; r++) {
        float s = siluf(acc2[m][n][r] + bb[n][r]);
        acc2[m][n][r] = s;
        p[m] += s * vv[n][r];
      }
  #pragma unroll
  for (int m = 0; m < 4; m++) {
    p[m] += __shfl_xor(p[m], 16);
    p[m] += __shfl_xor(p[m], 32);
  }
  if (lane < 16) {
    #pragma unroll
    for (int m = 0; m < 4; m++)
      atomicAdd(&sRed[jw + m * 16 + lr], p[m]);
  }
  __syncthreads();

  if constexpr (EPATH) {
    if (tid < 128)
      sAttW[tid] = fast_sig(sRed[tid] + battp[0]) * adjrow[tid];
    __syncthreads();
    float aw[4];
    #pragma unroll
    for (int m = 0; m < 4; m++) aw[m] = sAttW[jw + m * 16 + lr];
    f32x4 q[2];
    #pragma unroll
    for (int n = 0; n < 2; n++) { f32x4 z = {0.f,0.f,0.f,0.f}; q[n] = z; }
    #pragma unroll
    for (int m = 0; m < 4; m++)
      #pragma unroll
      for (int n = 0; n < 2; n++)
        q[n] += acc2[m][n] * aw[m];
    #pragma unroll
    for (int off = 1; off < 16; off <<= 1)
      #pragma unroll
      for (int n = 0; n < 2; n++)
        #pragma unroll
        for (int r = 0; r < 4; r++)
          q[n][r] += __shfl_xor(q[n][r], off);
    if (lr == 0) {
      #pragma unroll
      for (int n = 0; n < 2; n++)
        #pragma unroll
        for (int r = 0; r < 4; r++)
          atomicAdd(&sNM[kb + n * 16 + lg * 4 + r], q[n][r]);
    }
    __syncthreads();
    if (tid < 256) hcat_out[tid] = tobf(sNM[tid]);
  }
}

// ================= main edge kernel: one block = one (b,i), 1024 thr =================
__global__ __launch_bounds__(1024, 4) void k_edge(
    const float* __restrict__ coords, const float* __restrict__ adjm,
    const float* __restrict__ ef,
    const float* __restrict__ We1, const float* __restrict__ Wx1,
    const float* __restrict__ batt,
    const float* __restrict__ be2, const float* __restrict__ bx2,
    const float* __restrict__ bx3,
    const float* __restrict__ Watt, const float* __restrict__ Wx3,
    const float* __restrict__ hie, const float* __restrict__ hje,
    const float* __restrict__ hix, const float* __restrict__ hjx,
    const __bf16* __restrict__ wt_e, const __bf16* __restrict__ wt_x,
    const __bf16* __restrict__ w2e, const __bf16* __restrict__ w2x,
    __bf16* __restrict__ hcat, float* __restrict__ cupd)
{
  __shared__ __align__(16) __bf16 sE[128 * 72];
  __shared__ __align__(16) char sSb[128 * 512];
  __shared__ float shie[256], shix[256], slaste[256], slastx[256];
  __shared__ float sqv[128], sRed1[128], sRed2[128], sAttW[128], sNM[256], sCup[4];

  const int tid = threadIdx.x;
  const int bi = blockIdx.x;
  const int b = bi >> 7;

  const float cix = coords[bi * 3 + 0];
  const float ciy = coords[bi * 3 + 1];
  const float ciz = coords[bi * 3 + 2];

  if (tid < 128) { sRed1[tid] = 0.f; sRed2[tid] = 0.f; }
  else if (tid < 384) sNM[tid - 128] = 0.f;
  else if (tid < 388) sCup[tid - 384] = 0.f;
  if (tid < 256) {
    shie[tid] = hie[(size_t)bi * 256 + tid];
    shix[tid] = hix[(size_t)bi * 256 + tid];
    slaste[tid] = We1[576 * 256 + tid];
    slastx[tid] = Wx1[576 * 256 + tid];
  }
  if (tid >= 512 && tid < 640) {
    int j = tid - 512;
    int jg = b * 128 + j;
    float dx = cix - coords[jg * 3 + 0];
    float dy = ciy - coords[jg * 3 + 1];
    float dz = ciz - coords[jg * 3 + 2];
    sqv[j] = dx * dx + dy * dy + dz * dz;
  }
  const float* efb = ef + (size_t)bi * 8192;
  #pragma unroll
  for (int it = 0; it < 2; it++) {
    int idx = (tid + it * 1024) * 4;
    f32x4 v = *(const f32x4*)(efb + idx);
    bf16x4 pk;
    pk[0] = tobf(v[0]); pk[1] = tobf(v[1]); pk[2] = tobf(v[2]); pk[3] = tobf(v[3]);
    *(bf16x4*)(sE + (idx >> 6) * 72 + (idx & 63)) = pk;
  }
  __syncthreads();

  const float* adjrow = adjm + (size_t)bi * 128;

  egnn_path<true>(tid, sE, sSb, shie, slaste, sqv,
                  hje + (size_t)b * 32768, wt_e, w2e, be2, Watt,
                  sRed1, batt, sAttW, sNM, adjrow,
                  hcat + (size_t)bi * 512 + 256);
  egnn_path<false>(tid, sE, sSb, shix, slastx, sqv,
                   hjx + (size_t)b * 32768, wt_x, w2x, bx2, Wx3,
                   sRed2, nullptr, sAttW, sNM, adjrow, nullptr);

  // coord partial: sum over j
  if (tid < 128) {
    int j = tid;
    int jg = b * 128 + j;
    float ea = sRed2[j] + bx3[0];
    float wgt = ea * __builtin_amdgcn_rcpf(sqrtf(sqv[j] + 1e-5f) + 1.0f) * adjrow[j];
    float wx = wgt * (cix - coords[jg * 3 + 0]);
    float wy = wgt * (ciy - coords[jg * 3 + 1]);
    float wz = wgt * (ciz - coords[jg * 3 + 2]);
    #pragma unroll
    for (int off = 1; off < 64; off <<= 1) {
      wx += __shfl_xor(wx, off);
      wy += __shfl_xor(wy, off);
      wz += __shfl_xor(wz, off);
    }
    if ((tid & 63) == 0) {
      atomicAdd(&sCup[0], wx);
      atomicAdd(&sCup[1], wy);
      atomicAdd(&sCup[2], wz);
    }
  }
  __syncthreads();
  if (tid < 3) cupd[bi * 3 + tid] = sCup[tid];
}

extern "C" void kernel_launch(void* const* d_in, const int* in_sizes, int n_in,
                              void* d_out, int out_size, void* d_ws, size_t ws_size,
                              hipStream_t stream)
{
  const float* coords = (const float*)d_in[0];
  const float* invf  = (const float*)d_in[1];
  const float* adjm  = (const float*)d_in[2];
  const float* amask = (const float*)d_in[3];
  const float* ef    = (const float*)d_in[4];
  const float* We1   = (const float*)d_in[5];
  const float* be1   = (const float*)d_in[6];
  const float* We2   = (const float*)d_in[7];
  const float* be2   = (const float*)d_in[8];
  const float* Watt  = (const float*)d_in[9];
  const float* batt  = (const float*)d_in[10];
  const float* Wh1   = (const float*)d_in[11];
  const float* bh1   = (const float*)d_in[12];
  const float* Wh2   = (const float*)d_in[13];
  const float* bh2   = (const float*)d_in[14];
  const float* Wx1   = (const float*)d_in[15];
  const float* bx1   = (const float*)d_in[16];
  const float* Wx2   = (const float*)d_in[17];
  const float* bx2   = (const float*)d_in[18];
  const float* Wx3   = (const float*)d_in[19];
  const float* bx3   = (const float*)d_in[20];

  char* ws = (char*)d_ws;
  const size_t MB = 1u << 20;
  float* hie  = (float*)(ws + 0 * MB);
  float* hje  = (float*)(ws + 1 * MB);
  float* hix  = (float*)(ws + 2 * MB);
  float* hjx  = (float*)(ws + 3 * MB);
  __bf16* hcat = (__bf16*)(ws + 4 * MB);              // [1024][512]
  __bf16* h1b  = (__bf16*)(ws + 5 * MB);              // [1024][256]
  __bf16* wt_e = (__bf16*)(ws + 5 * MB + 524288);     // [256][576]
  __bf16* wt_x = (__bf16*)(ws + 5 * MB + 524288 + 294912);
  __bf16* w2e  = (__bf16*)(ws + 5 * MB + 524288 + 2 * 294912);
  __bf16* w2x  = (__bf16*)(ws + 5 * MB + 524288 + 2 * 294912 + 131072);
  __bf16* wh1t = (__bf16*)(ws + 5 * MB + 524288 + 2 * 294912 + 2 * 131072);
  __bf16* wh2t = (__bf16*)(ws + 5 * MB + 524288 + 2 * 294912 + 2 * 131072 + 262144);
  float* cupd  = (float*)(ws + 5 * MB + 524288 + 2 * 294912 + 3 * 131072 + 262144);

  float* out_coords = (float*)d_out;
  float* out_feats  = out_coords + 8 * 128 * 3;

  hipLaunchKernelGGL(k_prep, dim3(1024), dim3(256), 0, stream,
                     We1, Wx1, We2, Wx2, Wh1, Wh2, invf,
                     wt_e, wt_x, w2e, w2x, wh1t, wh2t, hcat);
  hipLaunchKernelGGL(k_nproj, dim3(16, 4), dim3(256), 0, stream,
                     hcat, wt_e, wt_x, be1, bx1, hie, hje, hix, hjx);
  hipLaunchKernelGGL(k_edge, dim3(1024), dim3(1024), 0, stream,
                     coords, adjm, ef, We1, Wx1, batt, be2, bx2, bx3, Watt, Wx3,
                     hie, hje, hix, hjx, wt_e, wt_x, w2e, w2x, hcat, cupd);
  hipLaunchKernelGGL(k_h1, dim3(16), dim3(256), 0, stream,
                     hcat, wh1t, bh1, h1b);
  hipLaunchKernelGGL(k_h2, dim3(16), dim3(256), 0, stream,
                     h1b, wh2t, bh2, amask, coords, cupd, out_feats, out_coords);
}